// Round 2
// baseline (122.299 us; speedup 1.0000x reference)
//
#include <hip/hip_runtime.h>
#include <stdint.h>
#include <math.h>

#define N     500
#define DIN   100
#define DE    200
#define DOUT  100
#define AROW  (2*DIN + DE)        // 400
#define NEG_BIG (-9000000000000000.0f)
#define SLOPE 0.2f

#define JT       32               // j-tile rows (MFMA M)
#define KSTEPS   13               // ceil(208/16): K padded 200 -> 208
#define ROWB     512              // LDS bytes per tile row (swizzle-safe, 256 bf16)
#define JCHUNKS  4                // flash-split of the j (softmax) axis
#define JCL      125              // 500 / 4
#define CTILES   4                // ceil(125/32)

typedef __attribute__((ext_vector_type(8)))  short short8;
typedef __attribute__((ext_vector_type(16))) float f32x16;

static __device__ __forceinline__ unsigned short f2bf(float f) {
  union { float f; uint32_t u; } v; v.f = f;
  uint32_t r = (v.u + 0x7FFFu + ((v.u >> 16) & 1u)) >> 16;   // RNE
  return (unsigned short)r;
}

// ---------------- kernel 1a: src, dst, ssrc, sdst ----------------
__global__ void precompute_kernel(const float* __restrict__ R,
                                  const float* __restrict__ A,
                                  const float* __restrict__ a2,
                                  float* __restrict__ src, float* __restrict__ dst,
                                  float* __restrict__ ssrc, float* __restrict__ sdst) {
  int i = blockIdx.x;
  int t = threadIdx.x;
  __shared__ float rrow[DIN];
  __shared__ float red[256];
  if (t < DIN) rrow[t] = R[i * DIN + t];
  __syncthreads();
  int o = -1; bool isSrc = false;
  if (t < DOUT) { o = t; isSrc = true; }
  else if (t >= 128 && t < 128 + DOUT) { o = t - 128; }
  float val = 0.f;
  if (o >= 0) {
    const float* arow = A + o * AROW + (isSrc ? 0 : DIN);
    #pragma unroll 4
    for (int d = 0; d < DIN; ++d) val += rrow[d] * arow[d];
    if (isSrc) src[i * DOUT + o] = val; else dst[i * DOUT + o] = val;
    red[t] = val * a2[o];
  } else red[t] = 0.f;
  __syncthreads();
  if (t == 0) { float s = 0; for (int k = 0; k < DOUT; ++k) s += red[k];       ssrc[i] = s; }
  if (t == 1) { float s = 0; for (int k = 0; k < DOUT; ++k) s += red[128 + k]; sdst[i] = s; }
}

// ---------------- kernel 1b: w[d] = sum_o a_ent[o,d]*a2[o] ----------------
__global__ void wvec_kernel(const float* __restrict__ A, const float* __restrict__ a2,
                            float* __restrict__ w) {
  int d = threadIdx.x;
  if (d < DE) {
    float s = 0.f;
    for (int o = 0; o < DOUT; ++o) s += A[o * AROW + 2 * DIN + d] * a2[o];
    w[d] = s;
  }
}

// ---------------- main fused kernel: one WG per (row i, j-chunk c) ----------------
__global__ __launch_bounds__(256, 4)
void gat_main(const float* __restrict__ E, const int* __restrict__ adj,
              const float* __restrict__ A,
              const float* __restrict__ dst,
              const float* __restrict__ ssrcA, const float* __restrict__ sdstA,
              const float* __restrict__ wv,
              float* __restrict__ pm, float* __restrict__ pz, float* __restrict__ ph) {
  __shared__ uint64_t lds64[JT * ROWB / 8];   // 16 KiB E tile (bf16, swizzled)
  __shared__ float e2raw[JT];
  char* ldsE = (char*)lds64;

  int bid  = blockIdx.x;
  int i    = bid >> 2;                 // row
  int cch  = bid & 3;                  // j-chunk
  int jbeg = cch * JCL;
  int jend = jbeg + JCL;

  int t    = threadIdx.x;
  int wave = t >> 6;
  int lane = t & 63;
  int c31  = lane & 31;
  int hi   = lane >> 5;
  int o    = wave * 32 + c31;          // 0..127 (pad >= 100)
  int oc   = o < DOUT ? o : DOUT - 1;
  bool ovalid = (o < DOUT);

  // B fragments: B[k=d][n=o] = a_ent[o,d]; wave3 col4 carries w[d]
  short8 bfrag[KSTEPS];
  #pragma unroll
  for (int k = 0; k < KSTEPS; ++k) {
    int d0 = k * 16 + hi * 8;
    float f[8];
    if (d0 + 8 <= DE) {
      if (ovalid) {
        const float* p = A + o * AROW + 2 * DIN + d0;
        #pragma unroll
        for (int e = 0; e < 8; ++e) f[e] = p[e];
      } else if (wave == 3 && c31 == 4) {
        #pragma unroll
        for (int e = 0; e < 8; ++e) f[e] = wv[d0 + e];
      } else {
        #pragma unroll
        for (int e = 0; e < 8; ++e) f[e] = 0.f;
      }
    } else {
      #pragma unroll
      for (int e = 0; e < 8; ++e) f[e] = 0.f;
    }
    short8 s;
    #pragma unroll
    for (int e = 0; e < 8; ++e) s[e] = (short)f2bf(f[e]);
    bfrag[k] = s;
  }

  float ssrc_i = ssrcA[i];
  const float* Erow = E + (size_t)i * N * DE;

  float m = -__builtin_inff();
  float Z = 0.f;
  float hacc = 0.f;

  for (int tile = 0; tile < CTILES; ++tile) {
    int j0 = jbeg + tile * JT;
    __syncthreads();
    // ---- stage E tile -> LDS bf16, XOR-swizzled ----
    for (int f4 = t; f4 < JT * 50; f4 += 256) {
      int row  = f4 / 50;
      int col4 = f4 % 50;
      int j = j0 + row;
      float4 v;
      if (j < jend) v = *(const float4*)(Erow + (size_t)j * DE + col4 * 4);
      else          v = make_float4(0.f, 0.f, 0.f, 0.f);
      ushort4 pk;
      pk.x = f2bf(v.x); pk.y = f2bf(v.y); pk.z = f2bf(v.z); pk.w = f2bf(v.w);
      int c = col4 * 8;
      int addr = row * ROWB + (c ^ ((row & 31) << 4));
      *(ushort4*)(ldsE + addr) = pk;
    }
    if (t < 64) {  // zero-pad d = 200..207
      int row = t >> 1;
      int c = 400 + (t & 1) * 8;
      int addr = row * ROWB + (c ^ ((row & 31) << 4));
      *(uint64_t*)(ldsE + addr) = 0ull;
    }
    __syncthreads();

    // ---- MFMA: acc[m=j, n=o] over K=208 ----
    f32x16 acc = {};
    #pragma unroll
    for (int k = 0; k < KSTEPS; ++k) {
      int row = c31;
      int c = k * 32 + hi * 16;
      int addr = row * ROWB + (c ^ ((row & 31) << 4));
      short8 af = *(const short8*)(ldsE + addr);
      acc = __builtin_amdgcn_mfma_f32_32x32x16_bf16(af, bfrag[k], acc, 0, 0, 0);
    }

    // wave3 col4 = E·w per row -> e2raw
    if (wave == 3 && c31 == 4) {
      #pragma unroll
      for (int r = 0; r < 16; ++r) {
        int row = (r & 3) + 8 * (r >> 2) + 4 * hi;
        e2raw[row] = acc[r];
      }
    }
    __syncthreads();

    // ---- scores + online softmax + h accumulation ----
    float s[16];
    float mt = -__builtin_inff();
    #pragma unroll
    for (int r = 0; r < 16; ++r) {
      int row = (r & 3) + 8 * (r >> 2) + 4 * hi;
      int j = j0 + row;
      float sv;
      if (j < jend) {
        float e2 = ssrc_i + sdstA[j] + e2raw[row];
        e2 = e2 > 0.f ? e2 : SLOPE * e2;
        sv = (adj[(size_t)i * N + j] > 0) ? e2 : NEG_BIG;
      } else sv = -__builtin_inff();
      s[r] = sv;
      mt = fmaxf(mt, sv);
    }
    mt = fmaxf(mt, __shfl_xor(mt, 32, 64));
    float mnew  = fmaxf(m, mt);
    float scale = __expf(m - mnew);       // m=-inf first tile -> 0
    float psum = 0.f, hadd = 0.f;
    #pragma unroll
    for (int r = 0; r < 16; ++r) {
      int row = (r & 3) + 8 * (r >> 2) + 4 * hi;
      int j = j0 + row;
      int jc = j < jend ? j : jend - 1;
      float pv = __expf(s[r] - mnew);     // 0 for pad / strongly-masked
      psum += pv;
      float eprime = acc[r] + dst[jc * DOUT + oc];   // ent + dst[j,o]
      hadd += pv * eprime;
    }
    psum += __shfl_xor(psum, 32, 64);
    Z    = Z * scale + psum;
    hacc = hacc * scale + hadd;
    m = mnew;
  }

  // ---- epilogue: combine halves, write partials ----
  hacc += __shfl_xor(hacc, 32, 64);
  int pidx = i * JCHUNKS + cch;
  if (hi == 0 && ovalid) ph[(size_t)pidx * DOUT + o] = hacc;
  if (t == 0) { pm[pidx] = m; pz[pidx] = Z; }
}

// ---------------- combine kernel: merge chunk partials ----------------
__global__ void combine_kernel(const float* __restrict__ src,
                               const float* __restrict__ pm, const float* __restrict__ pz,
                               const float* __restrict__ ph, float* __restrict__ out) {
  int i = blockIdx.x;
  int o = threadIdx.x;
  if (o >= DOUT) return;
  float M = -__builtin_inff();
  #pragma unroll
  for (int c = 0; c < JCHUNKS; ++c) M = fmaxf(M, pm[i * JCHUNKS + c]);
  float H = 0.f, Zt = 0.f;
  #pragma unroll
  for (int c = 0; c < JCHUNKS; ++c) {
    float w = __expf(pm[i * JCHUNKS + c] - M);
    H  += w * ph[(size_t)(i * JCHUNKS + c) * DOUT + o];
    Zt += w * pz[i * JCHUNKS + c];
  }
  float h = src[i * DOUT + o] + H / Zt;
  out[i * DOUT + o] = h > 0.f ? h : expm1f(h);
}

extern "C" void kernel_launch(void* const* d_in, const int* in_sizes, int n_in,
                              void* d_out, int out_size, void* d_ws, size_t ws_size,
                              hipStream_t stream) {
  const float* R   = (const float*)d_in[0];
  const float* E   = (const float*)d_in[1];
  const int*   adj = (const int*)d_in[2];
  const float* A   = (const float*)d_in[3];
  const float* a2  = (const float*)d_in[4];
  float* out = (float*)d_out;

  float* ws   = (float*)d_ws;
  float* src  = ws;                        // N*DOUT
  float* dst  = ws + N * DOUT;             // N*DOUT
  float* ssrc = ws + 2 * N * DOUT;         // N
  float* sdst = ssrc + N;                  // N
  float* wv   = sdst + N;                  // DE
  float* pm   = wv + DE;                   // N*JCHUNKS
  float* pz   = pm + N * JCHUNKS;          // N*JCHUNKS
  float* ph   = pz + N * JCHUNKS;          // N*JCHUNKS*DOUT

  precompute_kernel<<<N, 256, 0, stream>>>(R, A, a2, src, dst, ssrc, sdst);
  wvec_kernel<<<1, 256, 0, stream>>>(A, a2, wv);
  gat_main<<<N * JCHUNKS, 256, 0, stream>>>(E, adj, A, dst, ssrc, sdst, wv, pm, pz, ph);
  combine_kernel<<<N, 128, 0, stream>>>(src, pm, pz, ph, out);
}

// Round 3
// 76.341 us; speedup vs baseline: 1.6020x; 1.6020x over previous
//
#include <hip/hip_runtime.h>
#include <stdint.h>
#include <math.h>

#define N     500
#define DIN   100
#define DE    200
#define DOUT  100
#define AROW  (2*DIN + DE)        // 400
#define NEG_BIG (-9000000000000000.0f)
#define SLOPE 0.2f

#define JCH   8                   // j-chunks per row i
#define CROWS 63                  // ceil(500/8)
#define KP    512                 // Pbuf padded row length (j)
#define BK    720                 // Bcat row length: 512 (j) + 208 (d pad)
#define GSTR  209                 // gt LDS stride (odd -> no bank conflict)

typedef __attribute__((ext_vector_type(8)))  short short8;
typedef __attribute__((ext_vector_type(16))) float f32x16;

static __device__ __forceinline__ unsigned short f2bf(float f) {
  union { float f; uint32_t u; } v; v.f = f;
  uint32_t r = (v.u + 0x7FFFu + ((v.u >> 16) & 1u)) >> 16;   // RNE
  return (unsigned short)r;
}

// ---------- K1: src, ssrc, sdst, Bcat dst-columns, Pbuf j-pad zero ----------
__global__ void precompute_kernel(const float* __restrict__ R,
                                  const float* __restrict__ A,
                                  const float* __restrict__ a2,
                                  float* __restrict__ src,
                                  float* __restrict__ ssrc, float* __restrict__ sdst,
                                  unsigned short* __restrict__ Bcat,
                                  unsigned short* __restrict__ Pbuf) {
  int i = blockIdx.x;
  int t = threadIdx.x;
  __shared__ float rrow[DIN];
  __shared__ float red[256];
  if (t < DIN) rrow[t] = R[i * DIN + t];
  if (t < KP - N) Pbuf[i * KP + N + t] = 0;          // zero j-pad 500..511
  __syncthreads();
  int o = -1; bool isSrc = false;
  if (t < DOUT) { o = t; isSrc = true; }
  else if (t >= 128 && t < 128 + DOUT) { o = t - 128; }
  float val = 0.f;
  if (o >= 0) {
    const float* arow = A + o * AROW + (isSrc ? 0 : DIN);
    #pragma unroll 4
    for (int d = 0; d < DIN; ++d) val += rrow[d] * arow[d];
    if (isSrc) src[i * DOUT + o] = val;
    else       Bcat[o * BK + i] = f2bf(val);         // B[k=j=i][n=o] = dst[j,o]
    red[t] = val * a2[o];
  } else red[t] = 0.f;
  __syncthreads();
  if (t == 0) { float s = 0; for (int k = 0; k < DOUT; ++k) s += red[k];       ssrc[i] = s; }
  if (t == 1) { float s = 0; for (int k = 0; k < DOUT; ++k) s += red[128 + k]; sdst[i] = s; }
}

// ---------- K2: w[d] = sum_o a_ent[o,d]*a2[o] ----------
__global__ void wvec_kernel(const float* __restrict__ A, const float* __restrict__ a2,
                            float* __restrict__ w) {
  int d = threadIdx.x;
  if (d < DE) {
    float s = 0.f;
    for (int o = 0; o < DOUT; ++o) s += A[o * AROW + 2 * DIN + d] * a2[o];
    w[d] = s;
  }
}

// ---------- K2b: Bcat a_ent section + pads (one block per o) ----------
__global__ void bcat_kernel(const float* __restrict__ A, unsigned short* __restrict__ Bcat) {
  int o = blockIdx.x;
  int t = threadIdx.x;
  if (t < DE) Bcat[o * BK + KP + t] = f2bf(A[o * AROW + 2 * DIN + t]); // B[k=512+d][o]
  if (t < KP - N) Bcat[o * BK + N + t] = 0;                            // j-pad
  if (t >= 32 && t < 32 + (BK - KP - DE)) Bcat[o * BK + KP + DE + (t - 32)] = 0; // d-pad
}

// ---------- K3: streaming pass over E: scores p, Z, g accumulation ----------
__global__ __launch_bounds__(128)
void passA(const float* __restrict__ E, const int* __restrict__ adj,
           const float* __restrict__ ssrcA, const float* __restrict__ sdstA,
           const float* __restrict__ wv,
           unsigned short* __restrict__ Pbuf,
           float* __restrict__ gws, float* __restrict__ Zws) {
  int bid = blockIdx.x;
  int i = bid >> 3;
  int c = bid & 7;
  int jbeg = c * CROWS;
  int jend = jbeg + CROWS; if (jend > N) jend = N;

  int t = threadIdx.x;
  int wid = t >> 6;
  int lane = t & 63;

  float4 w4 = make_float4(0.f, 0.f, 0.f, 0.f);
  if (lane < 50) w4 = *(const float4*)(wv + lane * 4);

  float g0 = 0.f, g1 = 0.f, g2 = 0.f, g3 = 0.f, Z = 0.f;
  float ssrc_i = ssrcA[i];
  const float* Erow = E + (size_t)i * N * DE;

  for (int j = jbeg + wid; j < jend; j += 2) {
    float p = 0.f;
    float4 ev = make_float4(0.f, 0.f, 0.f, 0.f);
    if (adj[i * N + j] > 0) {
      if (lane < 50) ev = *(const float4*)(Erow + (size_t)j * DE + lane * 4);
      float d = ev.x * w4.x + ev.y * w4.y + ev.z * w4.z + ev.w * w4.w;
      d += __shfl_xor(d, 1);  d += __shfl_xor(d, 2);  d += __shfl_xor(d, 4);
      d += __shfl_xor(d, 8);  d += __shfl_xor(d, 16); d += __shfl_xor(d, 32);
      float e2 = ssrc_i + sdstA[j] + d;
      e2 = e2 > 0.f ? e2 : SLOPE * e2;
      p = __expf(e2);                 // no max-subtraction: |e2| small, f32 safe
      Z += p;
      g0 += p * ev.x; g1 += p * ev.y; g2 += p * ev.z; g3 += p * ev.w;
    }
    if (lane == 0) Pbuf[i * KP + j] = f2bf(p);
  }

  // cross-wave (2 waves) g/Z reduction
  __shared__ float gl[2][200];
  __shared__ float zl[2];
  if (lane < 50) { float* gp = &gl[wid][lane * 4]; gp[0] = g0; gp[1] = g1; gp[2] = g2; gp[3] = g3; }
  if (lane == 0) zl[wid] = Z;
  __syncthreads();
  if (wid == 0) {
    if (lane < 50) {
      float4 a = *(float4*)&gl[0][lane * 4];
      float4 b = *(float4*)&gl[1][lane * 4];
      float4 s = make_float4(a.x + b.x, a.y + b.y, a.z + b.z, a.w + b.w);
      *(float4*)(gws + ((size_t)(i * JCH + c)) * DE + lane * 4) = s;
    }
    if (lane == 0) Zws[i * JCH + c] = zl[0] + zl[1];
  }
}

// ---------- K4: combine — [P | g] @ [dst ; a_ent^T] via MFMA, epilogue ----------
__global__ __launch_bounds__(256)
void combine_kernel(const float* __restrict__ src,
                    const unsigned short* __restrict__ Pbuf,
                    const unsigned short* __restrict__ Bcat,
                    const float* __restrict__ gws, const float* __restrict__ Zws,
                    float* __restrict__ out) {
  int b = blockIdx.x;
  int t = threadIdx.x;
  int i0 = b * 32;
  __shared__ float gt[32 * GSTR];
  __shared__ float Zt[32];

  if (t < 32) {
    int i = i0 + t;
    float z = 1.f;
    if (i < N) { z = 0.f; for (int c = 0; c < JCH; ++c) z += Zws[i * JCH + c]; }
    Zt[t] = z;
  }
  // sum g over chunks into LDS (rows 32 x 208, zero-padded)
  for (int idx = t; idx < 32 * 52; idx += 256) {
    int r = idx / 52;
    int d4 = (idx % 52) * 4;
    int i = i0 + r;
    float4 s = make_float4(0.f, 0.f, 0.f, 0.f);
    if (i < N && d4 < DE) {
      for (int c = 0; c < JCH; ++c) {
        const float4 v = *(const float4*)(gws + ((size_t)(i * JCH + c)) * DE + d4);
        s.x += v.x; s.y += v.y; s.z += v.z; s.w += v.w;
      }
    }
    float* gp = &gt[r * GSTR + d4];
    gp[0] = s.x; gp[1] = s.y; gp[2] = s.z; gp[3] = s.w;
  }
  __syncthreads();

  int wave = t >> 6, lane = t & 63, c31 = lane & 31, hi = lane >> 5;
  int o = wave * 32 + c31;
  int arow = i0 + c31; if (arow > N - 1) arow = N - 1;

  f32x16 acc = {};
  for (int ks = 0; ks < 45; ++ks) {
    short8 a, bf;
    if (ks < 32) {
      a = *(const short8*)(Pbuf + (size_t)arow * KP + ks * 16 + hi * 8);
    } else {
      int d0 = (ks - 32) * 16 + hi * 8;
      const float* gp = &gt[c31 * GSTR + d0];
      #pragma unroll
      for (int e = 0; e < 8; ++e) a[e] = (short)f2bf(gp[e]);
    }
    if (o < DOUT) bf = *(const short8*)(Bcat + (size_t)o * BK + ks * 16 + hi * 8);
    else { short8 zz = {}; bf = zz; }
    acc = __builtin_amdgcn_mfma_f32_32x32x16_bf16(a, bf, acc, 0, 0, 0);
  }

  if (o < DOUT) {
    #pragma unroll
    for (int r = 0; r < 16; ++r) {
      int row = (r & 3) + 8 * (r >> 2) + 4 * hi;
      int i = i0 + row;
      if (i < N) {
        float h = src[i * DOUT + o] + acc[r] / Zt[row];
        out[i * DOUT + o] = h > 0.f ? h : expm1f(h);
      }
    }
  }
}

extern "C" void kernel_launch(void* const* d_in, const int* in_sizes, int n_in,
                              void* d_out, int out_size, void* d_ws, size_t ws_size,
                              hipStream_t stream) {
  const float* R   = (const float*)d_in[0];
  const float* E   = (const float*)d_in[1];
  const int*   adj = (const int*)d_in[2];
  const float* A   = (const float*)d_in[3];
  const float* a2  = (const float*)d_in[4];
  float* out = (float*)d_out;

  char* wsb = (char*)d_ws;
  float*          src  = (float*)(wsb + 0);          // 200,000 B
  float*          ssrc = (float*)(wsb + 200000);     //   2,000 B
  float*          sdst = (float*)(wsb + 202000);     //   2,000 B
  float*          wv   = (float*)(wsb + 204000);     //     800 B
  unsigned short* Bcat = (unsigned short*)(wsb + 204800);  // 144,000 B
  unsigned short* Pbuf = (unsigned short*)(wsb + 348800);  // 512,000 B
  float*          gws  = (float*)(wsb + 860800);     // 3,200,000 B
  float*          Zws  = (float*)(wsb + 4060800);    //  16,000 B  (total ~4.08 MB)

  precompute_kernel<<<N, 256, 0, stream>>>(R, A, a2, src, ssrc, sdst, Bcat, Pbuf);
  wvec_kernel<<<1, 256, 0, stream>>>(A, a2, wv);
  bcat_kernel<<<DOUT, 256, 0, stream>>>(A, Bcat);
  passA<<<N * JCH, 128, 0, stream>>>(E, adj, ssrc, sdst, wv, Pbuf, gws, Zws);
  combine_kernel<<<16, 256, 0, stream>>>(src, Pbuf, Bcat, gws, Zws, out);
}

// Round 4
// 64.382 us; speedup vs baseline: 1.8996x; 1.1857x over previous
//
#include <hip/hip_runtime.h>
#include <stdint.h>
#include <math.h>

#define N     500
#define DIN   100
#define DE    200
#define DOUT  100
#define AROW  (2*DIN + DE)        // 400
#define SLOPE 0.2f

#define JCH   8                   // j-chunks per row i
#define CROWS 63                  // ceil(500/8)
#define KP    512                 // Pbuf padded row length (j)
#define BK    720                 // Bcat row length: 512 (j) + 208 (d pad)
#define DEP   208                 // padded DE

typedef __attribute__((ext_vector_type(8)))  short short8;
typedef __attribute__((ext_vector_type(16))) float f32x16;

static __device__ __forceinline__ unsigned short f2bf(float f) {
  union { float f; uint32_t u; } v; v.f = f;
  uint32_t r = (v.u + 0x7FFFu + ((v.u >> 16) & 1u)) >> 16;   // RNE
  return (unsigned short)r;
}

// ---------- K1: merged setup ----------
// blocks 0..N-1   : per-i src/ssrc/sdst + Bcat dst-column + Pbuf j-pad
// block  N        : wv[d] = sum_o a_ent[o,d]*a2[o]
// blocks N+1..N+DOUT : Bcat a_ent rows + pads
__global__ __launch_bounds__(256)
void setup_kernel(const float* __restrict__ R, const float* __restrict__ A,
                  const float* __restrict__ a2,
                  float* __restrict__ src, float* __restrict__ ssrc,
                  float* __restrict__ sdst, float* __restrict__ wv,
                  unsigned short* __restrict__ Bcat, unsigned short* __restrict__ Pbuf) {
  int b = blockIdx.x, t = threadIdx.x;
  if (b < N) {
    int i = b;
    __shared__ float rrow[DIN];
    __shared__ float sred[4];
    if (t < DIN) rrow[t] = R[i * DIN + t];
    if (t < KP - N) Pbuf[i * KP + N + t] = 0;          // zero j-pad 500..511
    __syncthreads();
    int o = -1; bool isSrc = false;
    if (t < DOUT) { o = t; isSrc = true; }
    else if (t >= 128 && t < 128 + DOUT) { o = t - 128; }
    float val = 0.f;
    if (o >= 0) {
      const float* arow = A + o * AROW + (isSrc ? 0 : DIN);
      #pragma unroll 4
      for (int d = 0; d < DIN; ++d) val += rrow[d] * arow[d];
      if (isSrc) src[i * DOUT + o] = val;
      else       Bcat[o * BK + i] = f2bf(val);         // B[k=j=i][n=o] = dst[j,o]
    }
    float red = (o >= 0) ? val * a2[o] : 0.f;
    #pragma unroll
    for (int k = 1; k < 64; k <<= 1) red += __shfl_xor(red, k, 64);
    if ((t & 63) == 0) sred[t >> 6] = red;
    __syncthreads();
    if (t == 0)   ssrc[i] = sred[0] + sred[1];
    if (t == 128) sdst[i] = sred[2] + sred[3];
  } else if (b == N) {
    if (t < DE) {
      float s = 0.f;
      for (int o = 0; o < DOUT; ++o) s += A[o * AROW + 2 * DIN + t] * a2[o];
      wv[t] = s;
    }
  } else {
    int o = b - (N + 1);
    if (t < DE) Bcat[o * BK + KP + t] = f2bf(A[o * AROW + 2 * DIN + t]);
    if (t < KP - N) Bcat[o * BK + N + t] = 0;                                 // j-pad
    if (t >= 32 && t < 32 + (BK - KP - DE)) Bcat[o * BK + KP + DE + (t - 32)] = 0; // d-pad
  }
}

// ---------- K2: streaming pass over E (unroll-2 for MLP) ----------
__global__ __launch_bounds__(128)
void passA(const float* __restrict__ E, const int* __restrict__ adj,
           const float* __restrict__ ssrcA, const float* __restrict__ sdstA,
           const float* __restrict__ wv,
           unsigned short* __restrict__ Pbuf,
           float* __restrict__ gws, float* __restrict__ Zws) {
  int bid = blockIdx.x;
  int i = bid >> 3, c = bid & 7;
  int jbeg = c * CROWS;
  int jend = jbeg + CROWS; if (jend > N) jend = N;
  int t = threadIdx.x, wid = t >> 6, lane = t & 63;

  float4 w4 = make_float4(0.f, 0.f, 0.f, 0.f);
  if (lane < 50) w4 = *(const float4*)(wv + lane * 4);

  float4 g = make_float4(0.f, 0.f, 0.f, 0.f);
  float Z = 0.f;
  float ssrc_i = ssrcA[i];
  const float* Erow = E + (size_t)i * N * DE;
  const int* adjrow = adj + (size_t)i * N;

  int j = jbeg + wid;
  for (; j + 2 < jend; j += 4) {
    int a0 = adjrow[j], a1 = adjrow[j + 2];
    float4 ev0 = make_float4(0.f, 0.f, 0.f, 0.f);
    float4 ev1 = make_float4(0.f, 0.f, 0.f, 0.f);
    if (a0 > 0 && lane < 50) ev0 = *(const float4*)(Erow + (size_t)j * DE + lane * 4);
    if (a1 > 0 && lane < 50) ev1 = *(const float4*)(Erow + (size_t)(j + 2) * DE + lane * 4);
    float d0 = ev0.x * w4.x + ev0.y * w4.y + ev0.z * w4.z + ev0.w * w4.w;
    float d1 = ev1.x * w4.x + ev1.y * w4.y + ev1.z * w4.z + ev1.w * w4.w;
    #pragma unroll
    for (int k = 1; k < 64; k <<= 1) { d0 += __shfl_xor(d0, k, 64); d1 += __shfl_xor(d1, k, 64); }
    float p0 = 0.f, p1 = 0.f;
    if (a0 > 0) {
      float e2 = ssrc_i + sdstA[j] + d0;
      e2 = e2 > 0.f ? e2 : SLOPE * e2;
      p0 = __expf(e2); Z += p0;
      g.x += p0 * ev0.x; g.y += p0 * ev0.y; g.z += p0 * ev0.z; g.w += p0 * ev0.w;
    }
    if (a1 > 0) {
      float e2 = ssrc_i + sdstA[j + 2] + d1;
      e2 = e2 > 0.f ? e2 : SLOPE * e2;
      p1 = __expf(e2); Z += p1;
      g.x += p1 * ev1.x; g.y += p1 * ev1.y; g.z += p1 * ev1.z; g.w += p1 * ev1.w;
    }
    if (lane == 0) { Pbuf[i * KP + j] = f2bf(p0); Pbuf[i * KP + j + 2] = f2bf(p1); }
  }
  for (; j < jend; j += 2) {
    int a0 = adjrow[j];
    float4 ev0 = make_float4(0.f, 0.f, 0.f, 0.f);
    float p0 = 0.f;
    if (a0 > 0) {
      if (lane < 50) ev0 = *(const float4*)(Erow + (size_t)j * DE + lane * 4);
      float d0 = ev0.x * w4.x + ev0.y * w4.y + ev0.z * w4.z + ev0.w * w4.w;
      #pragma unroll
      for (int k = 1; k < 64; k <<= 1) d0 += __shfl_xor(d0, k, 64);
      float e2 = ssrc_i + sdstA[j] + d0;
      e2 = e2 > 0.f ? e2 : SLOPE * e2;
      p0 = __expf(e2); Z += p0;
      g.x += p0 * ev0.x; g.y += p0 * ev0.y; g.z += p0 * ev0.z; g.w += p0 * ev0.w;
    }
    if (lane == 0) Pbuf[i * KP + j] = f2bf(p0);
  }

  // cross-wave (2 waves) g/Z reduction
  __shared__ float gl[2][200];
  __shared__ float zl[2];
  if (lane < 50) *(float4*)&gl[wid][lane * 4] = g;
  if (lane == 0) zl[wid] = Z;
  __syncthreads();
  if (wid == 0) {
    if (lane < 50) {
      float4 a = *(float4*)&gl[0][lane * 4];
      float4 b = *(float4*)&gl[1][lane * 4];
      *(float4*)(gws + (size_t)(i * JCH + c) * DE + lane * 4) =
          make_float4(a.x + b.x, a.y + b.y, a.z + b.z, a.w + b.w);
    }
    if (lane == 0) Zws[i * JCH + c] = zl[0] + zl[1];
  }
}

// ---------- K3: fold chunk partials -> bf16 gsum + Zsum (parallel) ----------
__global__ __launch_bounds__(64)
void gsum_kernel(const float* __restrict__ gws, const float* __restrict__ Zws,
                 unsigned short* __restrict__ gsum, float* __restrict__ Zsum) {
  int i = blockIdx.x, t = threadIdx.x;
  if (t < 50) {
    float4 s = make_float4(0.f, 0.f, 0.f, 0.f);
    #pragma unroll
    for (int c = 0; c < JCH; ++c) {
      float4 v = *(const float4*)(gws + (size_t)(i * JCH + c) * DE + t * 4);
      s.x += v.x; s.y += v.y; s.z += v.z; s.w += v.w;
    }
    ushort4 pk; pk.x = f2bf(s.x); pk.y = f2bf(s.y); pk.z = f2bf(s.z); pk.w = f2bf(s.w);
    *(ushort4*)(gsum + (size_t)i * DEP + t * 4) = pk;
  } else if (t == 50) {
    ushort4 z = {0, 0, 0, 0};
    *(ushort4*)(gsum + (size_t)i * DEP + 200) = z;
    *(ushort4*)(gsum + (size_t)i * DEP + 204) = z;
  } else if (t == 51) {
    float z = 0.f;
    #pragma unroll
    for (int c = 0; c < JCH; ++c) z += Zws[i * JCH + c];
    Zsum[i] = z;
  }
}

// ---------- K4: combine — [P | gsum] @ [dst ; a_ent^T] via MFMA ----------
__global__ __launch_bounds__(256)
void combine_kernel(const float* __restrict__ src,
                    const unsigned short* __restrict__ Pbuf,
                    const unsigned short* __restrict__ Bcat,
                    const unsigned short* __restrict__ gsum,
                    const float* __restrict__ Zsum,
                    float* __restrict__ out) {
  int b = blockIdx.x;
  int t = threadIdx.x;
  int i0 = b * 32;
  int wave = t >> 6, lane = t & 63, c31 = lane & 31, hi = lane >> 5;
  int o = wave * 32 + c31;
  int arow = i0 + c31; if (arow > N - 1) arow = N - 1;

  const unsigned short* Prow = Pbuf + (size_t)arow * KP;
  const unsigned short* grow = gsum + (size_t)arow * DEP;

  f32x16 acc = {};
  #pragma unroll
  for (int ks = 0; ks < 45; ++ks) {
    short8 a, bf;
    if (ks < 32) a = *(const short8*)(Prow + ks * 16 + hi * 8);
    else         a = *(const short8*)(grow + (ks - 32) * 16 + hi * 8);
    if (o < DOUT) bf = *(const short8*)(Bcat + (size_t)o * BK + ks * 16 + hi * 8);
    else { short8 zz = {}; bf = zz; }
    acc = __builtin_amdgcn_mfma_f32_32x32x16_bf16(a, bf, acc, 0, 0, 0);
  }

  if (o < DOUT) {
    #pragma unroll
    for (int r = 0; r < 16; ++r) {
      int row = (r & 3) + 8 * (r >> 2) + 4 * hi;
      int i = i0 + row;
      if (i < N) {
        float h = src[i * DOUT + o] + acc[r] / Zsum[i];
        out[i * DOUT + o] = h > 0.f ? h : expm1f(h);
      }
    }
  }
}

extern "C" void kernel_launch(void* const* d_in, const int* in_sizes, int n_in,
                              void* d_out, int out_size, void* d_ws, size_t ws_size,
                              hipStream_t stream) {
  const float* R   = (const float*)d_in[0];
  const float* E   = (const float*)d_in[1];
  const int*   adj = (const int*)d_in[2];
  const float* A   = (const float*)d_in[3];
  const float* a2  = (const float*)d_in[4];
  float* out = (float*)d_out;

  char* wsb = (char*)d_ws;
  float*          src  = (float*)(wsb + 0);                // 200,000 B
  float*          ssrc = (float*)(wsb + 200000);           //   2,000 B
  float*          sdst = (float*)(wsb + 202000);           //   2,000 B
  float*          wv   = (float*)(wsb + 204000);           //     800 B
  unsigned short* Bcat = (unsigned short*)(wsb + 204800);  // 144,000 B
  unsigned short* Pbuf = (unsigned short*)(wsb + 348800);  // 512,000 B
  float*          gws  = (float*)(wsb + 860800);           // 3,200,000 B
  float*          Zws  = (float*)(wsb + 4060800);          //  16,000 B
  unsigned short* gsum = (unsigned short*)(wsb + 4076800); // 208,000 B
  float*          Zsum = (float*)(wsb + 4284800);          //   2,000 B

  setup_kernel<<<N + 1 + DOUT, 256, 0, stream>>>(R, A, a2, src, ssrc, sdst, wv, Bcat, Pbuf);
  passA<<<N * JCH, 128, 0, stream>>>(E, adj, ssrc, sdst, wv, Pbuf, gws, Zws);
  gsum_kernel<<<N, 64, 0, stream>>>(gws, Zws, gsum, Zsum);
  combine_kernel<<<16, 256, 0, stream>>>(src, Pbuf, Bcat, gsum, Zsum, out);
}

// Round 5
// 57.530 us; speedup vs baseline: 2.1258x; 1.1191x over previous
//
#include <hip/hip_runtime.h>
#include <stdint.h>
#include <math.h>

#define N     500
#define DIN   100
#define DE    200
#define DOUT  100
#define AROW  (2*DIN + DE)        // 400
#define SLOPE 0.2f

#define JCH   4                   // j-chunks per row i
#define CROWS 125                 // 500 / 4
#define KP    512                 // Pbuf padded row length (j)
#define BK    720                 // Bcat row length: 512 (j) + 208 (d pad)
#define DEP   208                 // padded DE (f32 gsum stride)
#define GZF   104000              // 500*208 floats to zero

typedef __attribute__((ext_vector_type(8)))  short short8;
typedef __attribute__((ext_vector_type(16))) float f32x16;

static __device__ __forceinline__ unsigned short f2bf(float f) {
  union { float f; uint32_t u; } v; v.f = f;
  uint32_t r = (v.u + 0x7FFFu + ((v.u >> 16) & 1u)) >> 16;   // RNE
  return (unsigned short)r;
}

// ---------- K1: merged setup ----------
// b in [0,N)        : per-i src/ssrc/sdst + Bcat dst-column + Pbuf j-pad
// b == N            : wv[d]
// b in [N+1, N+100] : Bcat a_ent rows + pads
// b in [601, 702]   : zero gsum
// b == 703          : zero Zsum
__global__ __launch_bounds__(256)
void setup_kernel(const float* __restrict__ R, const float* __restrict__ A,
                  const float* __restrict__ a2,
                  float* __restrict__ src, float* __restrict__ ssrc,
                  float* __restrict__ sdst, float* __restrict__ wv,
                  unsigned short* __restrict__ Bcat, unsigned short* __restrict__ Pbuf,
                  float* __restrict__ gsum, float* __restrict__ Zsum) {
  int b = blockIdx.x, t = threadIdx.x;
  if (b < N) {
    int i = b;
    __shared__ float rrow[DIN];
    __shared__ float sred[4];
    if (t < DIN) rrow[t] = R[i * DIN + t];
    if (t < KP - N) Pbuf[i * KP + N + t] = 0;          // zero j-pad 500..511
    __syncthreads();
    int o = -1; bool isSrc = false;
    if (t < DOUT) { o = t; isSrc = true; }
    else if (t >= 128 && t < 128 + DOUT) { o = t - 128; }
    float val = 0.f;
    if (o >= 0) {
      const float* arow = A + o * AROW + (isSrc ? 0 : DIN);
      #pragma unroll 4
      for (int d = 0; d < DIN; ++d) val += rrow[d] * arow[d];
      if (isSrc) src[i * DOUT + o] = val;
      else       Bcat[o * BK + i] = f2bf(val);         // B[k=j=i][n=o] = dst[j,o]
    }
    float red = (o >= 0) ? val * a2[o] : 0.f;
    #pragma unroll
    for (int k = 1; k < 64; k <<= 1) red += __shfl_xor(red, k, 64);
    if ((t & 63) == 0) sred[t >> 6] = red;
    __syncthreads();
    if (t == 0)   ssrc[i] = sred[0] + sred[1];
    if (t == 128) sdst[i] = sred[2] + sred[3];
  } else if (b == N) {
    if (t < DE) {
      float s = 0.f;
      for (int o = 0; o < DOUT; ++o) s += A[o * AROW + 2 * DIN + t] * a2[o];
      wv[t] = s;
    }
  } else if (b <= N + DOUT) {
    int o = b - (N + 1);
    if (t < DE) Bcat[o * BK + KP + t] = f2bf(A[o * AROW + 2 * DIN + t]);
    if (t < KP - N) Bcat[o * BK + N + t] = 0;                                 // j-pad
    if (t >= 32 && t < 32 + (BK - KP - DE)) Bcat[o * BK + KP + DE + (t - 32)] = 0; // d-pad
  } else if (b <= 702) {
    int off = (b - 601) * 1024 + t * 4;
    if (off < GZF) *(float4*)(gsum + off) = make_float4(0.f, 0.f, 0.f, 0.f);
  } else {
    if (t < 125) *(float4*)(Zsum + t * 4) = make_float4(0.f, 0.f, 0.f, 0.f);
  }
}

// ---------- K2: streaming pass over E (compacted active list, unroll-4) ----------
__global__ __launch_bounds__(256)
void passA(const float* __restrict__ E, const int* __restrict__ adj,
           const float* __restrict__ ssrcA, const float* __restrict__ sdstA,
           const float* __restrict__ wv,
           unsigned short* __restrict__ Pbuf,
           float* __restrict__ gsum, float* __restrict__ Zsum) {
  __shared__ int list[128];
  __shared__ int cntS;
  __shared__ float gl[4][200];
  __shared__ float zl[4];

  int bid = blockIdx.x;
  int i = bid >> 2, c = bid & 3;
  int jbeg = c * CROWS;
  int t = threadIdx.x, wid = t >> 6, lane = t & 63;

  if (t == 0) cntS = 0;
  __syncthreads();

  // ballot-compact active j's; write p=0 for inactive
  bool active = false;
  if (t < CROWS) active = (adj[(size_t)i * N + jbeg + t] > 0);
  unsigned long long mask = __ballot(active);
  int wbase = 0;
  if (lane == 0 && mask) wbase = atomicAdd(&cntS, __popcll(mask));
  wbase = __shfl(wbase, 0);
  if (active) {
    list[wbase + __popcll(mask & ((1ull << lane) - 1ull))] = jbeg + t;
  } else if (t < CROWS) {
    Pbuf[i * KP + jbeg + t] = 0;
  }
  __syncthreads();
  int cnt = cntS;

  float4 w4 = make_float4(0.f, 0.f, 0.f, 0.f);
  if (lane < 50) w4 = *(const float4*)(wv + lane * 4);
  float4 g = make_float4(0.f, 0.f, 0.f, 0.f);
  float Z = 0.f;
  float ssrc_i = ssrcA[i];
  const float* Erow = E + (size_t)i * N * DE;

  // main: 4 rows per wave per iteration, branch-free loads
  for (int base = wid * 4; base + 3 < cnt; base += 16) {
    int j0 = list[base], j1 = list[base + 1], j2 = list[base + 2], j3 = list[base + 3];
    float4 e0 = make_float4(0.f,0.f,0.f,0.f), e1 = e0, e2v = e0, e3 = e0;
    if (lane < 50) {
      e0  = *(const float4*)(Erow + (size_t)j0 * DE + lane * 4);
      e1  = *(const float4*)(Erow + (size_t)j1 * DE + lane * 4);
      e2v = *(const float4*)(Erow + (size_t)j2 * DE + lane * 4);
      e3  = *(const float4*)(Erow + (size_t)j3 * DE + lane * 4);
    }
    float d0 = e0.x*w4.x + e0.y*w4.y + e0.z*w4.z + e0.w*w4.w;
    float d1 = e1.x*w4.x + e1.y*w4.y + e1.z*w4.z + e1.w*w4.w;
    float d2 = e2v.x*w4.x + e2v.y*w4.y + e2v.z*w4.z + e2v.w*w4.w;
    float d3 = e3.x*w4.x + e3.y*w4.y + e3.z*w4.z + e3.w*w4.w;
    #pragma unroll
    for (int k = 1; k < 64; k <<= 1) {
      d0 += __shfl_xor(d0, k); d1 += __shfl_xor(d1, k);
      d2 += __shfl_xor(d2, k); d3 += __shfl_xor(d3, k);
    }
    float s0 = ssrc_i + sdstA[j0] + d0; s0 = s0 > 0.f ? s0 : SLOPE * s0;
    float s1 = ssrc_i + sdstA[j1] + d1; s1 = s1 > 0.f ? s1 : SLOPE * s1;
    float s2 = ssrc_i + sdstA[j2] + d2; s2 = s2 > 0.f ? s2 : SLOPE * s2;
    float s3 = ssrc_i + sdstA[j3] + d3; s3 = s3 > 0.f ? s3 : SLOPE * s3;
    float p0 = __expf(s0), p1 = __expf(s1), p2 = __expf(s2), p3 = __expf(s3);
    Z += (p0 + p1) + (p2 + p3);
    g.x += p0*e0.x + p1*e1.x + p2*e2v.x + p3*e3.x;
    g.y += p0*e0.y + p1*e1.y + p2*e2v.y + p3*e3.y;
    g.z += p0*e0.z + p1*e1.z + p2*e2v.z + p3*e3.z;
    g.w += p0*e0.w + p1*e1.w + p2*e2v.w + p3*e3.w;
    if (lane == 0) {
      Pbuf[i * KP + j0] = f2bf(p0); Pbuf[i * KP + j1] = f2bf(p1);
      Pbuf[i * KP + j2] = f2bf(p2); Pbuf[i * KP + j3] = f2bf(p3);
    }
  }
  // tail: < 4 entries
  for (int idx = (cnt & ~3) + wid; idx < cnt; idx += 4) {
    int j = list[idx];
    float4 ev = make_float4(0.f,0.f,0.f,0.f);
    if (lane < 50) ev = *(const float4*)(Erow + (size_t)j * DE + lane * 4);
    float d = ev.x*w4.x + ev.y*w4.y + ev.z*w4.z + ev.w*w4.w;
    #pragma unroll
    for (int k = 1; k < 64; k <<= 1) d += __shfl_xor(d, k);
    float s = ssrc_i + sdstA[j] + d; s = s > 0.f ? s : SLOPE * s;
    float p = __expf(s);
    Z += p;
    g.x += p*ev.x; g.y += p*ev.y; g.z += p*ev.z; g.w += p*ev.w;
    if (lane == 0) Pbuf[i * KP + j] = f2bf(p);
  }

  // block-reduce g, Z; atomically fold into per-row sums
  if (lane < 50) *(float4*)&gl[wid][lane * 4] = g;
  if (lane == 0) zl[wid] = Z;
  __syncthreads();
  if (t < 200) {
    float s = gl[0][t] + gl[1][t] + gl[2][t] + gl[3][t];
    atomicAdd(gsum + (size_t)i * DEP + t, s);
  }
  if (t == 200) atomicAdd(Zsum + i, zl[0] + zl[1] + zl[2] + zl[3]);
}

// ---------- K3: combine — [P | g] @ [dst ; a_ent^T] via MFMA ----------
__global__ __launch_bounds__(256)
void combine_kernel(const float* __restrict__ src,
                    const unsigned short* __restrict__ Pbuf,
                    const unsigned short* __restrict__ Bcat,
                    const float* __restrict__ gsum,
                    const float* __restrict__ Zsum,
                    float* __restrict__ out) {
  int b = blockIdx.x;
  int t = threadIdx.x;
  int i0 = b * 32;
  int wave = t >> 6, lane = t & 63, c31 = lane & 31, hi = lane >> 5;
  int o = wave * 32 + c31;
  int arow = i0 + c31; if (arow > N - 1) arow = N - 1;

  const unsigned short* Prow = Pbuf + (size_t)arow * KP;
  const float* grow = gsum + (size_t)arow * DEP;

  f32x16 acc = {};
  #pragma unroll
  for (int ks = 0; ks < 45; ++ks) {
    short8 a, bf;
    if (ks < 32) {
      a = *(const short8*)(Prow + ks * 16 + hi * 8);
    } else {
      int d0 = (ks - 32) * 16 + hi * 8;
      float4 ga = *(const float4*)(grow + d0);
      float4 gb = *(const float4*)(grow + d0 + 4);
      a[0] = (short)f2bf(ga.x); a[1] = (short)f2bf(ga.y);
      a[2] = (short)f2bf(ga.z); a[3] = (short)f2bf(ga.w);
      a[4] = (short)f2bf(gb.x); a[5] = (short)f2bf(gb.y);
      a[6] = (short)f2bf(gb.z); a[7] = (short)f2bf(gb.w);
    }
    if (o < DOUT) bf = *(const short8*)(Bcat + (size_t)o * BK + ks * 16 + hi * 8);
    else { short8 zz = {}; bf = zz; }
    acc = __builtin_amdgcn_mfma_f32_32x32x16_bf16(a, bf, acc, 0, 0, 0);
  }

  if (o < DOUT) {
    #pragma unroll
    for (int r = 0; r < 16; ++r) {
      int row = (r & 3) + 8 * (r >> 2) + 4 * hi;
      int i = i0 + row;
      if (i < N) {
        float h = src[i * DOUT + o] + acc[r] / Zsum[i];
        out[i * DOUT + o] = h > 0.f ? h : expm1f(h);
      }
    }
  }
}

extern "C" void kernel_launch(void* const* d_in, const int* in_sizes, int n_in,
                              void* d_out, int out_size, void* d_ws, size_t ws_size,
                              hipStream_t stream) {
  const float* R   = (const float*)d_in[0];
  const float* E   = (const float*)d_in[1];
  const int*   adj = (const int*)d_in[2];
  const float* A   = (const float*)d_in[3];
  const float* a2  = (const float*)d_in[4];
  float* out = (float*)d_out;

  char* wsb = (char*)d_ws;
  float*          src  = (float*)(wsb + 0);                // 200,000 B
  float*          ssrc = (float*)(wsb + 200000);           //   2,000 B
  float*          sdst = (float*)(wsb + 202000);           //   2,000 B
  float*          wv   = (float*)(wsb + 204000);           //     800 B
  unsigned short* Bcat = (unsigned short*)(wsb + 204800);  // 144,000 B
  unsigned short* Pbuf = (unsigned short*)(wsb + 348800);  // 512,000 B
  float*          gsum = (float*)(wsb + 860800);           // 416,000 B (f32, atomic)
  float*          Zsum = (float*)(wsb + 1276800);          //   2,000 B

  setup_kernel<<<704, 256, 0, stream>>>(R, A, a2, src, ssrc, sdst, wv, Bcat, Pbuf, gsum, Zsum);
  passA<<<N * JCH, 256, 0, stream>>>(E, adj, ssrc, sdst, wv, Pbuf, gsum, Zsum);
  combine_kernel<<<16, 256, 0, stream>>>(src, Pbuf, Bcat, gsum, Zsum, out);
}

// Round 6
// 54.863 us; speedup vs baseline: 2.2292x; 1.0486x over previous
//
#include <hip/hip_runtime.h>
#include <stdint.h>
#include <math.h>

#define N     500
#define DIN   100
#define DE    200
#define DOUT  100
#define AROW  (2*DIN + DE)        // 400
#define SLOPE 0.2f

#define JCH   2                   // j-chunks per row i
#define CROWS 250                 // 500 / 2
#define KP    512                 // Pbuf padded row length (j)
#define BK    720                 // Bcat row length: 512 (j) + 208 (d pad)
#define DEP   208                 // padded DE (f32 gsum stride)
#define GZF   104000              // 500*208 floats to zero

typedef __attribute__((ext_vector_type(8)))  short short8;
typedef __attribute__((ext_vector_type(16))) float f32x16;

static __device__ __forceinline__ unsigned short f2bf(float f) {
  union { float f; uint32_t u; } v; v.f = f;
  uint32_t r = (v.u + 0x7FFFu + ((v.u >> 16) & 1u)) >> 16;   // RNE
  return (unsigned short)r;
}

// ---------- K1: merged setup ----------
__global__ __launch_bounds__(256)
void setup_kernel(const float* __restrict__ R, const float* __restrict__ A,
                  const float* __restrict__ a2,
                  float* __restrict__ src, float* __restrict__ ssrc,
                  float* __restrict__ sdst, float* __restrict__ wv,
                  unsigned short* __restrict__ Bcat, unsigned short* __restrict__ Pbuf,
                  float* __restrict__ gsum, float* __restrict__ Zsum) {
  int b = blockIdx.x, t = threadIdx.x;
  if (b < N) {
    int i = b;
    __shared__ float rrow[DIN];
    __shared__ float sred[4];
    if (t < DIN) rrow[t] = R[i * DIN + t];
    if (t < KP - N) Pbuf[i * KP + N + t] = 0;          // zero j-pad 500..511
    __syncthreads();
    int o = -1; bool isSrc = false;
    if (t < DOUT) { o = t; isSrc = true; }
    else if (t >= 128 && t < 128 + DOUT) { o = t - 128; }
    float val = 0.f;
    if (o >= 0) {
      const float* arow = A + o * AROW + (isSrc ? 0 : DIN);
      #pragma unroll 4
      for (int d = 0; d < DIN; ++d) val += rrow[d] * arow[d];
      if (isSrc) src[i * DOUT + o] = val;
      else       Bcat[o * BK + i] = f2bf(val);         // B[k=j=i][n=o] = dst[j,o]
    }
    float red = (o >= 0) ? val * a2[o] : 0.f;
    #pragma unroll
    for (int k = 1; k < 64; k <<= 1) red += __shfl_xor(red, k, 64);
    if ((t & 63) == 0) sred[t >> 6] = red;
    __syncthreads();
    if (t == 0)   ssrc[i] = sred[0] + sred[1];
    if (t == 128) sdst[i] = sred[2] + sred[3];
  } else if (b == N) {
    if (t < DE) {
      float s = 0.f;
      for (int o = 0; o < DOUT; ++o) s += A[o * AROW + 2 * DIN + t] * a2[o];
      wv[t] = s;
    }
  } else if (b <= N + DOUT) {
    int o = b - (N + 1);
    if (t < DE) Bcat[o * BK + KP + t] = f2bf(A[o * AROW + 2 * DIN + t]);
    if (t < KP - N) Bcat[o * BK + N + t] = 0;                                 // j-pad
    if (t >= 32 && t < 32 + (BK - KP - DE)) Bcat[o * BK + KP + DE + (t - 32)] = 0; // d-pad
  } else if (b <= 702) {
    int off = (b - 601) * 1024 + t * 4;
    if (off < GZF) *(float4*)(gsum + off) = make_float4(0.f, 0.f, 0.f, 0.f);
  } else {
    if (t < 125) *(float4*)(Zsum + t * 4) = make_float4(0.f, 0.f, 0.f, 0.f);
  }
}

// ---------- K2: streaming pass over E (compacted list, unroll-8) ----------
__global__ __launch_bounds__(256, 4)
void passA(const float* __restrict__ E, const int* __restrict__ adj,
           const float* __restrict__ ssrcA, const float* __restrict__ sdstA,
           const float* __restrict__ wv,
           unsigned short* __restrict__ Pbuf,
           float* __restrict__ gsum, float* __restrict__ Zsum) {
  __shared__ int list[CROWS + 6];
  __shared__ float bias[CROWS + 6];     // ssrc_i + sdst[j] per compacted slot
  __shared__ int cntS;
  __shared__ float gl[4][200];
  __shared__ float zl[4];

  int bid = blockIdx.x;
  int i = bid >> 1, c = bid & 1;
  int jbeg = c * CROWS;
  int t = threadIdx.x, wid = t >> 6, lane = t & 63;

  if (t == 0) cntS = 0;
  __syncthreads();

  float ssrc_i = ssrcA[i];
  // ballot-compact active j's; write p=0 for inactive
  bool active = false;
  if (t < CROWS) active = (adj[(size_t)i * N + jbeg + t] > 0);
  unsigned long long mask = __ballot(active);
  int wbase = 0;
  if (lane == 0 && mask) wbase = atomicAdd(&cntS, __popcll(mask));
  wbase = __shfl(wbase, 0);
  if (active) {
    int slot = wbase + __popcll(mask & ((1ull << lane) - 1ull));
    list[slot] = jbeg + t;
    bias[slot] = ssrc_i + sdstA[jbeg + t];
  } else if (t < CROWS) {
    Pbuf[i * KP + jbeg + t] = 0;
  }
  __syncthreads();
  int cnt = cntS;

  float4 w4 = make_float4(0.f, 0.f, 0.f, 0.f);
  if (lane < 50) w4 = *(const float4*)(wv + lane * 4);
  float4 g = make_float4(0.f, 0.f, 0.f, 0.f);
  float Z = 0.f;
  const float* Erow = E + (size_t)i * N * DE;

  // main: 8 rows per wave per iteration, branch-free loads
  for (int base = wid * 8; base + 7 < cnt; base += 32) {
    int jr[8];
    float bi[8];
    #pragma unroll
    for (int r = 0; r < 8; ++r) { jr[r] = list[base + r]; bi[r] = bias[base + r]; }
    float4 ev[8];
    if (lane < 50) {
      #pragma unroll
      for (int r = 0; r < 8; ++r)
        ev[r] = *(const float4*)(Erow + (size_t)jr[r] * DE + lane * 4);
    } else {
      #pragma unroll
      for (int r = 0; r < 8; ++r) ev[r] = make_float4(0.f, 0.f, 0.f, 0.f);
    }
    float d[8];
    #pragma unroll
    for (int r = 0; r < 8; ++r)
      d[r] = ev[r].x * w4.x + ev[r].y * w4.y + ev[r].z * w4.z + ev[r].w * w4.w;
    #pragma unroll
    for (int k = 1; k < 64; k <<= 1) {
      #pragma unroll
      for (int r = 0; r < 8; ++r) d[r] += __shfl_xor(d[r], k);
    }
    float p[8];
    float zacc = 0.f;
    #pragma unroll
    for (int r = 0; r < 8; ++r) {
      float s = bi[r] + d[r];
      s = s > 0.f ? s : SLOPE * s;
      p[r] = __expf(s);
      zacc += p[r];
    }
    Z += zacc;
    #pragma unroll
    for (int r = 0; r < 8; ++r) {
      g.x += p[r] * ev[r].x; g.y += p[r] * ev[r].y;
      g.z += p[r] * ev[r].z; g.w += p[r] * ev[r].w;
    }
    if (lane == 0) {
      #pragma unroll
      for (int r = 0; r < 8; ++r) Pbuf[i * KP + jr[r]] = f2bf(p[r]);
    }
  }
  // tail: remaining < 8 entries, one row per wave round-robin
  for (int idx = (cnt & ~7) + wid; idx < cnt; idx += 4) {
    int j = list[idx];
    float bi = bias[idx];
    float4 ev = make_float4(0.f, 0.f, 0.f, 0.f);
    if (lane < 50) ev = *(const float4*)(Erow + (size_t)j * DE + lane * 4);
    float d = ev.x * w4.x + ev.y * w4.y + ev.z * w4.z + ev.w * w4.w;
    #pragma unroll
    for (int k = 1; k < 64; k <<= 1) d += __shfl_xor(d, k);
    float s = bi + d; s = s > 0.f ? s : SLOPE * s;
    float p = __expf(s);
    Z += p;
    g.x += p * ev.x; g.y += p * ev.y; g.z += p * ev.z; g.w += p * ev.w;
    if (lane == 0) Pbuf[i * KP + j] = f2bf(p);
  }

  // block-reduce g, Z; atomically fold into per-row sums
  if (lane < 50) *(float4*)&gl[wid][lane * 4] = g;
  if (lane == 0) zl[wid] = Z;
  __syncthreads();
  if (t < 200) {
    float s = gl[0][t] + gl[1][t] + gl[2][t] + gl[3][t];
    atomicAdd(gsum + (size_t)i * DEP + t, s);
  }
  if (t == 200) atomicAdd(Zsum + i, zl[0] + zl[1] + zl[2] + zl[3]);
}

// ---------- K3: combine — [P | g] @ [dst ; a_ent^T] via MFMA ----------
// 64 blocks x 64 threads: one wave per (i-tile, o-wave)
__global__ __launch_bounds__(64)
void combine_kernel(const float* __restrict__ src,
                    const unsigned short* __restrict__ Pbuf,
                    const unsigned short* __restrict__ Bcat,
                    const float* __restrict__ gsum,
                    const float* __restrict__ Zsum,
                    float* __restrict__ out) {
  int b = blockIdx.x;
  int i0 = (b >> 2) * 32;
  int ow = b & 3;
  int t = threadIdx.x;                  // 0..63
  int c31 = t & 31, hi = t >> 5;
  int o = ow * 32 + c31;
  int arow = i0 + c31; if (arow > N - 1) arow = N - 1;

  const unsigned short* Prow = Pbuf + (size_t)arow * KP;
  const float* grow = gsum + (size_t)arow * DEP;

  f32x16 acc = {};
  #pragma unroll
  for (int ks = 0; ks < 45; ++ks) {
    short8 a, bf;
    if (ks < 32) {
      a = *(const short8*)(Prow + ks * 16 + hi * 8);
    } else {
      int d0 = (ks - 32) * 16 + hi * 8;
      float4 ga = *(const float4*)(grow + d0);
      float4 gb = *(const float4*)(grow + d0 + 4);
      a[0] = (short)f2bf(ga.x); a[1] = (short)f2bf(ga.y);
      a[2] = (short)f2bf(ga.z); a[3] = (short)f2bf(ga.w);
      a[4] = (short)f2bf(gb.x); a[5] = (short)f2bf(gb.y);
      a[6] = (short)f2bf(gb.z); a[7] = (short)f2bf(gb.w);
    }
    if (o < DOUT) bf = *(const short8*)(Bcat + (size_t)o * BK + ks * 16 + hi * 8);
    else { short8 zz = {}; bf = zz; }
    acc = __builtin_amdgcn_mfma_f32_32x32x16_bf16(a, bf, acc, 0, 0, 0);
  }

  if (o < DOUT) {
    #pragma unroll
    for (int r = 0; r < 16; ++r) {
      int row = (r & 3) + 8 * (r >> 2) + 4 * hi;
      int i = i0 + row;
      if (i < N) {
        float h = src[i * DOUT + o] + acc[r] / Zsum[i];
        out[i * DOUT + o] = h > 0.f ? h : expm1f(h);
      }
    }
  }
}

extern "C" void kernel_launch(void* const* d_in, const int* in_sizes, int n_in,
                              void* d_out, int out_size, void* d_ws, size_t ws_size,
                              hipStream_t stream) {
  const float* R   = (const float*)d_in[0];
  const float* E   = (const float*)d_in[1];
  const int*   adj = (const int*)d_in[2];
  const float* A   = (const float*)d_in[3];
  const float* a2  = (const float*)d_in[4];
  float* out = (float*)d_out;

  char* wsb = (char*)d_ws;
  float*          src  = (float*)(wsb + 0);                // 200,000 B
  float*          ssrc = (float*)(wsb + 200000);           //   2,000 B
  float*          sdst = (float*)(wsb + 202000);           //   2,000 B
  float*          wv   = (float*)(wsb + 204000);           //     800 B
  unsigned short* Bcat = (unsigned short*)(wsb + 204800);  // 144,000 B
  unsigned short* Pbuf = (unsigned short*)(wsb + 348800);  // 512,000 B
  float*          gsum = (float*)(wsb + 860800);           // 416,000 B (f32, atomic)
  float*          Zsum = (float*)(wsb + 1276800);          //   2,000 B

  setup_kernel<<<704, 256, 0, stream>>>(R, A, a2, src, ssrc, sdst, wv, Bcat, Pbuf, gsum, Zsum);
  passA<<<N * JCH, 256, 0, stream>>>(E, adj, ssrc, sdst, wv, Pbuf, gsum, Zsum);
  combine_kernel<<<64, 64, 0, stream>>>(src, Pbuf, Bcat, gsum, Zsum, out);
}